// Round 1
// 1022.315 us; speedup vs baseline: 1.0526x; 1.0526x over previous
//
#include <hip/hip_runtime.h>
#include <stdint.h>

typedef __bf16 bf16;
typedef bf16 bf16x8 __attribute__((ext_vector_type(8)));
typedef bf16 bf16x4 __attribute__((ext_vector_type(4)));
typedef float f32x4 __attribute__((ext_vector_type(4)));

#define DIM   1024
#define TMAX  16
#define NTPL  64
#define BATCH 2048
#define SLEN  77

__device__ __forceinline__ void gl_lds16(const void* g, void* l) {
  __builtin_amdgcn_global_load_lds(
      (const __attribute__((address_space(1))) void*)g,
      (__attribute__((address_space(3))) void*)l, 16, 0, 0);
}

// ---------------- bucket by time_step (1 block) ----------------
__global__ void bucket_k(const int* __restrict__ ts, int* __restrict__ perm,
                         int* __restrict__ bstart) {
  __shared__ int cnt[TMAX], base[TMAX], cur[TMAX];
  int tid = threadIdx.x;
  if (tid < TMAX) { cnt[tid] = 0; cur[tid] = 0; }
  __syncthreads();
  for (int b = tid; b < BATCH; b += 256) atomicAdd(&cnt[ts[b]], 1);
  __syncthreads();
  if (tid == 0) {
    int a = 0;
    for (int t = 0; t < TMAX; ++t) { base[t] = a; bstart[t] = a; a += cnt[t]; }
    bstart[TMAX] = a;
  }
  __syncthreads();
  for (int b = tid; b < BATCH; b += 256) {
    int t = ts[b];
    perm[base[t] + atomicAdd(&cur[t], 1)] = b;
  }
}

// ---------------- fp32 -> bf16 conversions ----------------
__global__ void cvt_bf16_k(const float* __restrict__ src, bf16* __restrict__ dst) {
  int idx = blockIdx.x * 256 + threadIdx.x;
  float4 v = ((const float4*)src)[idx];
  bf16x4 o = {(bf16)v.x, (bf16)v.y, (bf16)v.z, (bf16)v.w};
  ((bf16x4*)dst)[idx] = o;
}

// textual_query -> upper half of xcat rows (row stride 2*DIM)
__global__ void cvt_tq_k(const float* __restrict__ tq, bf16* __restrict__ xcat) {
  int idx = blockIdx.x * 256 + threadIdx.x;  // BATCH*DIM/4 total
  int b = idx >> 8, c4 = idx & 255;
  float4 v = ((const float4*)(tq + (size_t)b * DIM))[c4];
  bf16x4 o = {(bf16)v.x, (bf16)v.y, (bf16)v.z, (bf16)v.w};
  *(bf16x4*)(xcat + (size_t)b * 2 * DIM + DIM + c4 * 4) = o;
}

// ---------------- 64x64-tile bf16 B^T GEMM: C[M,N] = A[M,K]*B[N,K]^T + bias ----------------
// 4 waves in 2x2, each wave 32x32 (2x2 16x16 frags). Double-buffered LDS,
// STAGE(next) issued before compute(cur): per-iter cost max(L,C) not L+C.
// grid: (N/64, M/64). 512 blocks for M=2048,N=1024 -> 2 blocks/CU.
__global__ __launch_bounds__(256, 4) void gemm_bt64(
    const bf16* __restrict__ A, int lda, const bf16* __restrict__ B, int ldb,
    const float* __restrict__ bias, bf16* __restrict__ C, int ldc,
    float* __restrict__ Cf, int N, int K, int relu) {
  __shared__ bf16 As[2][64 * 32];
  __shared__ bf16 Bs[2][64 * 32];
  const int tid = threadIdx.x;
  const int rowBase = blockIdx.y * 64, colBase = blockIdx.x * 64;

  const int r = tid >> 2, kq = tid & 3;            // 64 rows x 4 k-octets
  const bf16* ag = A + (size_t)(rowBase + r) * lda + kq * 8;
  int bn = colBase + r; if (bn > N - 1) bn = N - 1;
  const bf16* bg = B + (size_t)bn * ldb + kq * 8;

  const int wave = tid >> 6, lane = tid & 63;
  const int wm = wave >> 1, wn = wave & 1;
  const int mr = lane & 15, quad = lane >> 4;

  f32x4 acc[2][2];
#pragma unroll
  for (int i = 0; i < 2; ++i)
#pragma unroll
    for (int j = 0; j < 2; ++j) acc[i][j] = (f32x4){0.f, 0.f, 0.f, 0.f};

  // prologue: stage tile 0
  gl_lds16(ag, &As[0][tid * 8]);
  gl_lds16(bg, &Bs[0][tid * 8]);
  __syncthreads();

  const int nk = K >> 5;
  for (int t = 0; t < nk; ++t) {
    const int cur = t & 1;
    if (t + 1 < nk) {  // issue next-tile loads BEFORE compute
      gl_lds16(ag + (t + 1) * 32, &As[cur ^ 1][tid * 8]);
      gl_lds16(bg + (t + 1) * 32, &Bs[cur ^ 1][tid * 8]);
    }
    bf16x8 af[2], bfr[2];
#pragma unroll
    for (int i = 0; i < 2; ++i)
      af[i] = *(const bf16x8*)&As[cur][(wm * 32 + i * 16 + mr) * 32 + quad * 8];
#pragma unroll
    for (int j = 0; j < 2; ++j)
      bfr[j] = *(const bf16x8*)&Bs[cur][(wn * 32 + j * 16 + mr) * 32 + quad * 8];
#pragma unroll
    for (int i = 0; i < 2; ++i)
#pragma unroll
      for (int j = 0; j < 2; ++j)
        acc[i][j] = __builtin_amdgcn_mfma_f32_16x16x32_bf16(af[i], bfr[j], acc[i][j], 0, 0, 0);
    __syncthreads();  // drains vmcnt (prefetch landed) + lgkm; both buffers safe
  }

  const int r0 = quad * 4;
#pragma unroll
  for (int i = 0; i < 2; ++i) {
    int gm = rowBase + wm * 32 + i * 16 + r0;
#pragma unroll
    for (int j = 0; j < 2; ++j) {
      int gn = colBase + wn * 32 + j * 16 + mr;
      if (gn < N) {
        float bv = bias ? bias[gn] : 0.f;
#pragma unroll
        for (int rr = 0; rr < 4; ++rr) {
          float v = acc[i][j][rr] + bv;
          if (relu) v = fmaxf(v, 0.f);
          C[(size_t)(gm + rr) * ldc + gn] = (bf16)v;
          if (Cf) Cf[(size_t)(gm + rr) * ldc + gn] = v;
        }
      }
    }
  }
}

// ---------------- stage 1: per-t gathered GEMM (64x64 tiles) ----------------
// x1[perm] = tsent[perm] @ W1[t]^T + W1_b[t] -> xcat[:, 0:DIM]
__global__ __launch_bounds__(256, 4) void gemm_stage1(
    const bf16* __restrict__ tsbf, const bf16* __restrict__ W1bf,
    const float* __restrict__ W1b, const int* __restrict__ perm,
    const int* __restrict__ bstart, bf16* __restrict__ xcat) {
  const int t = blockIdx.z;
  const int s0 = bstart[t];
  const int cnt = bstart[t + 1] - s0;
  const int by = blockIdx.y;
  if (by * 64 >= cnt) return;
  __shared__ bf16 As[2][64 * 32];
  __shared__ bf16 Bs[2][64 * 32];
  const int tid = threadIdx.x;
  const int colBase = blockIdx.x * 64;
  const bf16* Bmat = W1bf + ((size_t)t << 20);

  const int r = tid >> 2, kq = tid & 3;
  const int lr0 = by * 64 + r;
  const int src = perm[s0 + (lr0 < cnt ? lr0 : 0)];
  const bf16* ag = tsbf + (size_t)src * DIM + kq * 8;
  const bf16* bg = Bmat + (size_t)(colBase + r) * DIM + kq * 8;

  const int wave = tid >> 6, lane = tid & 63;
  const int wm = wave >> 1, wn = wave & 1;
  const int mr = lane & 15, quad = lane >> 4;

  f32x4 acc[2][2];
#pragma unroll
  for (int i = 0; i < 2; ++i)
#pragma unroll
    for (int j = 0; j < 2; ++j) acc[i][j] = (f32x4){0.f, 0.f, 0.f, 0.f};

  gl_lds16(ag, &As[0][tid * 8]);
  gl_lds16(bg, &Bs[0][tid * 8]);
  __syncthreads();

  const int nk = DIM >> 5;
  for (int t2 = 0; t2 < nk; ++t2) {
    const int cur = t2 & 1;
    if (t2 + 1 < nk) {
      gl_lds16(ag + (t2 + 1) * 32, &As[cur ^ 1][tid * 8]);
      gl_lds16(bg + (t2 + 1) * 32, &Bs[cur ^ 1][tid * 8]);
    }
    bf16x8 af[2], bfr[2];
#pragma unroll
    for (int i = 0; i < 2; ++i)
      af[i] = *(const bf16x8*)&As[cur][(wm * 32 + i * 16 + mr) * 32 + quad * 8];
#pragma unroll
    for (int j = 0; j < 2; ++j)
      bfr[j] = *(const bf16x8*)&Bs[cur][(wn * 32 + j * 16 + mr) * 32 + quad * 8];
#pragma unroll
    for (int i = 0; i < 2; ++i)
#pragma unroll
      for (int j = 0; j < 2; ++j)
        acc[i][j] = __builtin_amdgcn_mfma_f32_16x16x32_bf16(af[i], bfr[j], acc[i][j], 0, 0, 0);
    __syncthreads();
  }

  const int r0 = quad * 4;
#pragma unroll
  for (int i = 0; i < 2; ++i) {
    int lr = by * 64 + wm * 32 + i * 16 + r0;
#pragma unroll
    for (int j = 0; j < 2; ++j) {
      int gn = colBase + wn * 32 + j * 16 + mr;
      float bv = W1b[t * DIM + gn];
#pragma unroll
      for (int rr = 0; rr < 4; ++rr) {
        if (lr + rr < cnt) {
          int bidx = perm[s0 + lr + rr];
          xcat[(size_t)bidx * 2 * DIM + gn] = (bf16)(acc[i][j][rr] + bv);
        }
      }
    }
  }
}

// ---------------- softmax over 64 templates (1 wave per row) ----------------
__global__ __launch_bounds__(256) void softmax64_k(const bf16* __restrict__ logits,
                                                   float* __restrict__ out) {
  int row = blockIdx.x * 4 + (threadIdx.x >> 6);
  int lane = threadIdx.x & 63;
  float v = (float)logits[row * NTPL + lane];
  float mx = v;
#pragma unroll
  for (int o = 32; o; o >>= 1) mx = fmaxf(mx, __shfl_xor(mx, o));
  float e = __expf(v - mx);
  float s = e;
#pragma unroll
  for (int o = 32; o; o >>= 1) s += __shfl_xor(s, o);
  out[row * NTPL + lane] = e / s;
}

// ---------------- fused word attention: per-wave online softmax, no per-word syncs ----
// Wave w handles words s = w, w+4, ... Each wave computes the full 1024-dim dot:
// lane l owns dims {4l+256j, j=0..3} (coalesced 1KB segments). One final merge.
__global__ __launch_bounds__(256) void attn_k(
    const float* __restrict__ x, const float* __restrict__ attn_w,
    const float* __restrict__ attn_b, const float* __restrict__ feats,
    float* __restrict__ words, float* __restrict__ ct) {
  const int b = blockIdx.x;
  const int tid = threadIdx.x;
  const int wave = tid >> 6, lane = tid & 63;
  const float* fb = feats + (size_t)b * SLEN * DIM;

  // v[j] = x[d] * attn_w[d] for dims d = 4*lane + 256*j
  float4 vj[4];
#pragma unroll
  for (int j = 0; j < 4; ++j) {
    int d = 4 * lane + 256 * j;
    float4 xv = *(const float4*)(x + (size_t)b * DIM + d);
    float4 aw = *(const float4*)(attn_w + d);
    vj[j] = make_float4(xv.x * aw.x, xv.y * aw.y, xv.z * aw.z, xv.w * aw.w);
  }
  const float ab = attn_b[0];

  __shared__ float s_acc[4][DIM];
  __shared__ float s_m[4], s_l[4], s_sc[SLEN];

  float m = -1e30f, l = 0.f;
  float4 acc[4];
#pragma unroll
  for (int j = 0; j < 4; ++j) acc[j] = make_float4(0.f, 0.f, 0.f, 0.f);

  // preload first row for this wave
  float4 f[4];
  {
    const float* fr = fb + (size_t)wave * DIM;
#pragma unroll
    for (int j = 0; j < 4; ++j) f[j] = *(const float4*)(fr + 4 * lane + 256 * j);
  }

  for (int s = wave; s < SLEN; s += 4) {
    float4 fn[4];
    if (s + 4 < SLEN) {
      const float* fr = fb + (size_t)(s + 4) * DIM;
#pragma unroll
      for (int j = 0; j < 4; ++j) fn[j] = *(const float4*)(fr + 4 * lane + 256 * j);
    }
    float p = 0.f;
#pragma unroll
    for (int j = 0; j < 4; ++j)
      p += f[j].x * vj[j].x + f[j].y * vj[j].y + f[j].z * vj[j].z + f[j].w * vj[j].w;
#pragma unroll
    for (int o = 32; o; o >>= 1) p += __shfl_xor(p, o);
    float score = p + ab;
    if (lane == 0) s_sc[s] = score;

    float mn = fmaxf(m, score);
    float scale = __expf(m - mn);
    float w = __expf(score - mn);
    l = l * scale + w;
#pragma unroll
    for (int j = 0; j < 4; ++j) {
      acc[j].x = acc[j].x * scale + w * f[j].x;
      acc[j].y = acc[j].y * scale + w * f[j].y;
      acc[j].z = acc[j].z * scale + w * f[j].z;
      acc[j].w = acc[j].w * scale + w * f[j].w;
    }
    m = mn;
    if (s + 4 < SLEN) {
#pragma unroll
      for (int j = 0; j < 4; ++j) f[j] = fn[j];
    }
  }

  // write wave partials
#pragma unroll
  for (int j = 0; j < 4; ++j)
    *(float4*)&s_acc[wave][4 * lane + 256 * j] = acc[j];
  if (lane == 0) { s_m[wave] = m; s_l[wave] = l; }
  __syncthreads();

  const float gm = fmaxf(fmaxf(s_m[0], s_m[1]), fmaxf(s_m[2], s_m[3]));
  float sc0 = __expf(s_m[0] - gm), sc1 = __expf(s_m[1] - gm);
  float sc2 = __expf(s_m[2] - gm), sc3 = __expf(s_m[3] - gm);
  const float L = s_l[0] * sc0 + s_l[1] * sc1 + s_l[2] * sc2 + s_l[3] * sc3;
  const float inv = 1.f / L;

  // thread tid owns dims 4*tid..4*tid+3
  float4 a0 = *(const float4*)&s_acc[0][4 * tid];
  float4 a1 = *(const float4*)&s_acc[1][4 * tid];
  float4 a2 = *(const float4*)&s_acc[2][4 * tid];
  float4 a3 = *(const float4*)&s_acc[3][4 * tid];
  float4 o;
  o.x = (a0.x * sc0 + a1.x * sc1 + a2.x * sc2 + a3.x * sc3) * inv;
  o.y = (a0.y * sc0 + a1.y * sc1 + a2.y * sc2 + a3.y * sc3) * inv;
  o.z = (a0.z * sc0 + a1.z * sc1 + a2.z * sc2 + a3.z * sc3) * inv;
  o.w = (a0.w * sc0 + a1.w * sc1 + a2.w * sc2 + a3.w * sc3) * inv;
  ((float4*)(ct + (size_t)b * DIM))[tid] = o;

  if (tid < SLEN) words[(size_t)b * SLEN + tid] = __expf(s_sc[tid] - gm) * inv;
}

extern "C" void kernel_launch(void* const* d_in, const int* in_sizes, int n_in,
                              void* d_out, int out_size, void* d_ws, size_t ws_size,
                              hipStream_t stream) {
  const float* feats = (const float*)d_in[0];
  const float* tsent = (const float*)d_in[1];
  const float* tq    = (const float*)d_in[2];
  const int*   tstep = (const int*)d_in[3];
  const float* W1w = (const float*)d_in[4];
  const float* W1b = (const float*)d_in[5];
  const float* W2w = (const float*)d_in[6];
  const float* W2b = (const float*)d_in[7];
  const float* m1w = (const float*)d_in[8];
  const float* m1b = (const float*)d_in[9];
  const float* m2w = (const float*)d_in[10];
  const float* m2b = (const float*)d_in[11];
  const float* m3w = (const float*)d_in[12];
  const float* m3b = (const float*)d_in[13];
  const float* attw = (const float*)d_in[14];
  const float* attb = (const float*)d_in[15];

  char* p = (char*)d_ws;
  auto alloc = [&](size_t bytes) { char* q = p; p += (bytes + 255) & ~(size_t)255; return q; };
  int*  perm   = (int*)alloc(BATCH * 4);
  int*  bstart = (int*)alloc(17 * 4);
  bf16* tsbf = (bf16*)alloc((size_t)BATCH * DIM * 2);
  bf16* W1bf = (bf16*)alloc((size_t)TMAX * DIM * DIM * 2);
  bf16* W2bf = (bf16*)alloc((size_t)DIM * 2 * DIM * 2);
  bf16* m1bf = (bf16*)alloc((size_t)DIM * DIM * 2);
  bf16* m2bf = (bf16*)alloc((size_t)DIM * DIM * 2);
  bf16* m3bf = (bf16*)alloc((size_t)NTPL * DIM * 2);
  bf16* xcat = (bf16*)alloc((size_t)BATCH * 2 * DIM * 2);  // [x1 | tq] bf16, lda=2048
  bf16* xbf  = (bf16*)alloc((size_t)BATCH * DIM * 2);
  float* xf  = (float*)alloc((size_t)BATCH * DIM * 4);     // fp32 x for attention
  bf16* h1   = (bf16*)alloc((size_t)BATCH * DIM * 2);
  bf16* h2   = (bf16*)alloc((size_t)BATCH * DIM * 2);
  bf16* lg   = (bf16*)alloc((size_t)BATCH * NTPL * 2);

  float* out_td = (float*)d_out;
  float* out_w  = out_td + (size_t)BATCH * NTPL;
  float* out_ct = out_w + (size_t)BATCH * SLEN;

  bucket_k<<<1, 256, 0, stream>>>(tstep, perm, bstart);
  cvt_bf16_k<<<(TMAX * DIM * DIM) / 1024, 256, 0, stream>>>(W1w, W1bf);
  cvt_bf16_k<<<(BATCH * DIM) / 1024, 256, 0, stream>>>(tsent, tsbf);
  cvt_bf16_k<<<(DIM * 2 * DIM) / 1024, 256, 0, stream>>>(W2w, W2bf);
  cvt_bf16_k<<<(DIM * DIM) / 1024, 256, 0, stream>>>(m1w, m1bf);
  cvt_bf16_k<<<(DIM * DIM) / 1024, 256, 0, stream>>>(m2w, m2bf);
  cvt_bf16_k<<<(NTPL * DIM) / 1024, 256, 0, stream>>>(m3w, m3bf);
  cvt_tq_k<<<(BATCH * DIM) / 1024, 256, 0, stream>>>(tq, xcat);

  // x1 (gathered, per-t) -> xcat[:, 0:DIM]
  gemm_stage1<<<dim3(DIM / 64, BATCH / 64, TMAX), 256, 0, stream>>>(
      tsbf, W1bf, W1b, perm, bstart, xcat);
  // x = xcat @ W2^T + b   (K=2048), also keep fp32 copy for attention
  gemm_bt64<<<dim3(DIM / 64, BATCH / 64), 256, 0, stream>>>(
      xcat, 2 * DIM, W2bf, 2 * DIM, W2b, xbf, DIM, xf, DIM, 2 * DIM, 0);
  // h1 = relu(x @ m1^T + b)
  gemm_bt64<<<dim3(DIM / 64, BATCH / 64), 256, 0, stream>>>(
      xbf, DIM, m1bf, DIM, m1b, h1, DIM, nullptr, DIM, DIM, 1);
  // h2 = relu(h1 @ m2^T + b)
  gemm_bt64<<<dim3(DIM / 64, BATCH / 64), 256, 0, stream>>>(
      h1, DIM, m2bf, DIM, m2b, h2, DIM, nullptr, DIM, DIM, 1);
  // logits = h2 @ m3^T + b  (N=64)
  gemm_bt64<<<dim3(1, BATCH / 64), 256, 0, stream>>>(
      h2, DIM, m3bf, DIM, m3b, lg, NTPL, nullptr, NTPL, DIM, 0);
  softmax64_k<<<BATCH / 4, 256, 0, stream>>>(lg, out_td);
  attn_k<<<BATCH, 256, 0, stream>>>(xf, attw, attb, feats, out_w, out_ct);
}

// Round 2
// 992.119 us; speedup vs baseline: 1.0846x; 1.0304x over previous
//
#include <hip/hip_runtime.h>
#include <stdint.h>

typedef __bf16 bf16;
typedef bf16 bf16x8 __attribute__((ext_vector_type(8)));
typedef bf16 bf16x4 __attribute__((ext_vector_type(4)));
typedef float f32x4 __attribute__((ext_vector_type(4)));

#define DIM   1024
#define TMAX  16
#define NTPL  64
#define BATCH 2048
#define SLEN  77

__device__ __forceinline__ void gl_lds16(const void* g, void* l) {
  __builtin_amdgcn_global_load_lds(
      (const __attribute__((address_space(1))) void*)g,
      (__attribute__((address_space(3))) void*)l, 16, 0, 0);
}

// ================= fused prep: all fp32->bf16 conversions + tq scatter + bucket ======
// Block ranges (1024 elems per block, 256 thr x float4):
//  [0,16384)        W1w  -> W1bf
//  [16384,18432)    tsent-> tsbf
//  [18432,20480)    W2w  -> W2bf
//  [20480,21504)    m1w  -> m1bf
//  [21504,22528)    m2w  -> m2bf
//  [22528,22592)    m3w  -> m3bf
//  [22592,24640)    tq   -> xcat upper half (row stride 2*DIM)
//  24640            bucket time_step -> perm/bstart
__global__ void prep_k(const float* __restrict__ W1w, bf16* __restrict__ W1bf,
                       const float* __restrict__ tsent, bf16* __restrict__ tsbf,
                       const float* __restrict__ W2w, bf16* __restrict__ W2bf,
                       const float* __restrict__ m1w, bf16* __restrict__ m1bf,
                       const float* __restrict__ m2w, bf16* __restrict__ m2bf,
                       const float* __restrict__ m3w, bf16* __restrict__ m3bf,
                       const float* __restrict__ tq, bf16* __restrict__ xcat,
                       const int* __restrict__ ts, int* __restrict__ perm,
                       int* __restrict__ bstart) {
  const int blk = blockIdx.x;
  const int tid = threadIdx.x;
  if (blk < 22592) {
    const float* src; bf16* dst; int base;
    if (blk < 16384)      { src = W1w;   dst = W1bf; base = blk; }
    else if (blk < 18432) { src = tsent; dst = tsbf; base = blk - 16384; }
    else if (blk < 20480) { src = W2w;   dst = W2bf; base = blk - 18432; }
    else if (blk < 21504) { src = m1w;   dst = m1bf; base = blk - 20480; }
    else if (blk < 22528) { src = m2w;   dst = m2bf; base = blk - 21504; }
    else                  { src = m3w;   dst = m3bf; base = blk - 22528; }
    int idx = base * 256 + tid;
    float4 v = ((const float4*)src)[idx];
    bf16x4 o = {(bf16)v.x, (bf16)v.y, (bf16)v.z, (bf16)v.w};
    ((bf16x4*)dst)[idx] = o;
  } else if (blk < 24640) {
    int idx = (blk - 22592) * 256 + tid;
    int b = idx >> 8, c4 = idx & 255;
    float4 v = ((const float4*)(tq + (size_t)b * DIM))[c4];
    bf16x4 o = {(bf16)v.x, (bf16)v.y, (bf16)v.z, (bf16)v.w};
    *(bf16x4*)(xcat + (size_t)b * 2 * DIM + DIM + c4 * 4) = o;
  } else {
    __shared__ int cnt[TMAX], base_s[TMAX], cur[TMAX];
    if (tid < TMAX) { cnt[tid] = 0; cur[tid] = 0; }
    __syncthreads();
    for (int b = tid; b < BATCH; b += 256) atomicAdd(&cnt[ts[b]], 1);
    __syncthreads();
    if (tid == 0) {
      int a = 0;
      for (int t = 0; t < TMAX; ++t) { base_s[t] = a; bstart[t] = a; a += cnt[t]; }
      bstart[TMAX] = a;
    }
    __syncthreads();
    for (int b = tid; b < BATCH; b += 256) {
      int t = ts[b];
      perm[base_s[t] + atomicAdd(&cur[t], 1)] = b;
    }
  }
}

// ================= pipelined GEMM core =================
// 4 LDS buffers, depth-2 prefetch via global_load_lds, counted vmcnt, raw barriers.
// Per iter: stage(t+2); s_waitcnt vmcnt(4) [tile t landed, t+1/t+2 in flight];
// s_barrier; ds_read frags(t); MFMA.  One barrier/iter, never vmcnt(0) until tail.
// Hazards: stage(t+2) overwrites buf last read at iter t-2 -> reads done before
// barrier(t-1) < stage issue point (needs exactly 4 buffers). Reads(t) covered by
// own vmcnt(4) + barrier.
__device__ __forceinline__ void gemm_pipe(
    bf16 (*As)[64 * 32], bf16 (*Bs)[64 * 32],
    const bf16* ag, const bf16* bg, int nk, int tid,
    int wm, int wn, int mr, int quad, f32x4 (&acc)[2][2]) {
  auto stage = [&](int t) {
    int buf = t & 3;
    gl_lds16(ag + t * 32, &As[buf][tid * 8]);
    gl_lds16(bg + t * 32, &Bs[buf][tid * 8]);
  };
  auto compute = [&](int t) {
    int buf = t & 3;
    bf16x8 af[2], bfr[2];
#pragma unroll
    for (int i = 0; i < 2; ++i)
      af[i] = *(const bf16x8*)&As[buf][(wm * 32 + i * 16 + mr) * 32 + quad * 8];
#pragma unroll
    for (int j = 0; j < 2; ++j)
      bfr[j] = *(const bf16x8*)&Bs[buf][(wn * 32 + j * 16 + mr) * 32 + quad * 8];
#pragma unroll
    for (int i = 0; i < 2; ++i)
#pragma unroll
      for (int j = 0; j < 2; ++j)
        acc[i][j] = __builtin_amdgcn_mfma_f32_16x16x32_bf16(af[i], bfr[j], acc[i][j], 0, 0, 0);
  };
  stage(0);
  stage(1);
  for (int t = 0; t < nk - 2; ++t) {
    stage(t + 2);
    asm volatile("s_waitcnt vmcnt(4)" ::: "memory");
    __builtin_amdgcn_sched_barrier(0);
    __builtin_amdgcn_s_barrier();
    __builtin_amdgcn_sched_barrier(0);
    compute(t);
  }
  asm volatile("s_waitcnt vmcnt(2)" ::: "memory");
  __builtin_amdgcn_sched_barrier(0);
  __builtin_amdgcn_s_barrier();
  __builtin_amdgcn_sched_barrier(0);
  compute(nk - 2);
  asm volatile("s_waitcnt vmcnt(0)" ::: "memory");
  __builtin_amdgcn_sched_barrier(0);
  __builtin_amdgcn_s_barrier();
  __builtin_amdgcn_sched_barrier(0);
  compute(nk - 1);
}

// ---------------- generic 64x64 B^T GEMM: C[M,N] = A[M,K]*B[N,K]^T + bias ----------------
__global__ __launch_bounds__(256, 4) void gemm_bt64(
    const bf16* __restrict__ A, int lda, const bf16* __restrict__ B, int ldb,
    const float* __restrict__ bias, bf16* __restrict__ C, int ldc,
    float* __restrict__ Cf, int N, int K, int relu) {
  __shared__ bf16 As[4][64 * 32];
  __shared__ bf16 Bs[4][64 * 32];
  const int tid = threadIdx.x;
  const int rowBase = blockIdx.y * 64, colBase = blockIdx.x * 64;

  const int r = tid >> 2, kq = tid & 3;  // 64 rows x 4 k-octets
  const bf16* ag = A + (size_t)(rowBase + r) * lda + kq * 8;
  int bn = colBase + r; if (bn > N - 1) bn = N - 1;
  const bf16* bg = B + (size_t)bn * ldb + kq * 8;

  const int wave = tid >> 6, lane = tid & 63;
  const int wm = wave >> 1, wn = wave & 1;
  const int mr = lane & 15, quad = lane >> 4;

  f32x4 acc[2][2];
#pragma unroll
  for (int i = 0; i < 2; ++i)
#pragma unroll
    for (int j = 0; j < 2; ++j) acc[i][j] = (f32x4){0.f, 0.f, 0.f, 0.f};

  gemm_pipe(As, Bs, ag, bg, K >> 5, tid, wm, wn, mr, quad, acc);

  const int r0 = quad * 4;
#pragma unroll
  for (int i = 0; i < 2; ++i) {
    int gm = rowBase + wm * 32 + i * 16 + r0;
#pragma unroll
    for (int j = 0; j < 2; ++j) {
      int gn = colBase + wn * 32 + j * 16 + mr;
      if (gn < N) {
        float bv = bias ? bias[gn] : 0.f;
#pragma unroll
        for (int rr = 0; rr < 4; ++rr) {
          float v = acc[i][j][rr] + bv;
          if (relu) v = fmaxf(v, 0.f);
          C[(size_t)(gm + rr) * ldc + gn] = (bf16)v;
          if (Cf) Cf[(size_t)(gm + rr) * ldc + gn] = v;
        }
      }
    }
  }
}

// ---------------- stage 1: per-t gathered GEMM (64x64 tiles, pipelined) ----------------
__global__ __launch_bounds__(256, 4) void gemm_stage1(
    const bf16* __restrict__ tsbf, const bf16* __restrict__ W1bf,
    const float* __restrict__ W1b, const int* __restrict__ perm,
    const int* __restrict__ bstart, bf16* __restrict__ xcat) {
  const int t = blockIdx.z;
  const int s0 = bstart[t];
  const int cnt = bstart[t + 1] - s0;
  const int by = blockIdx.y;
  if (by * 64 >= cnt) return;
  __shared__ bf16 As[4][64 * 32];
  __shared__ bf16 Bs[4][64 * 32];
  const int tid = threadIdx.x;
  const int colBase = blockIdx.x * 64;
  const bf16* Bmat = W1bf + ((size_t)t << 20);

  const int r = tid >> 2, kq = tid & 3;
  const int lr0 = by * 64 + r;
  const int src = perm[s0 + (lr0 < cnt ? lr0 : 0)];
  const bf16* ag = tsbf + (size_t)src * DIM + kq * 8;
  const bf16* bg = Bmat + (size_t)(colBase + r) * DIM + kq * 8;

  const int wave = tid >> 6, lane = tid & 63;
  const int wm = wave >> 1, wn = wave & 1;
  const int mr = lane & 15, quad = lane >> 4;

  f32x4 acc[2][2];
#pragma unroll
  for (int i = 0; i < 2; ++i)
#pragma unroll
    for (int j = 0; j < 2; ++j) acc[i][j] = (f32x4){0.f, 0.f, 0.f, 0.f};

  gemm_pipe(As, Bs, ag, bg, DIM >> 5, tid, wm, wn, mr, quad, acc);

  const int r0 = quad * 4;
#pragma unroll
  for (int i = 0; i < 2; ++i) {
    int lr = by * 64 + wm * 32 + i * 16 + r0;
#pragma unroll
    for (int j = 0; j < 2; ++j) {
      int gn = colBase + wn * 32 + j * 16 + mr;
      float bv = W1b[t * DIM + gn];
#pragma unroll
      for (int rr = 0; rr < 4; ++rr) {
        if (lr + rr < cnt) {
          int bidx = perm[s0 + lr + rr];
          xcat[(size_t)bidx * 2 * DIM + gn] = (bf16)(acc[i][j][rr] + bv);
        }
      }
    }
  }
}

// ---------------- m3 GEMM (N=64) with fused softmax -> out_td fp32 ----------------
// Each block: 64 batch rows x all 64 template logits, then row softmax in LDS.
__global__ __launch_bounds__(256) void gemm_m3sm(
    const bf16* __restrict__ A, const bf16* __restrict__ B,
    const float* __restrict__ bias, float* __restrict__ out) {
  __shared__ bf16 As[4][64 * 32];
  __shared__ bf16 Bs[4][64 * 32];
  __shared__ float ls[64][65];  // +1 pad: conflict-free epilogue writes
  const int tid = threadIdx.x;
  const int rowBase = blockIdx.x * 64;

  const int r = tid >> 2, kq = tid & 3;
  const bf16* ag = A + (size_t)(rowBase + r) * DIM + kq * 8;
  const bf16* bg = B + (size_t)r * DIM + kq * 8;  // N=64 rows exactly

  const int wave = tid >> 6, lane = tid & 63;
  const int wm = wave >> 1, wn = wave & 1;
  const int mr = lane & 15, quad = lane >> 4;

  f32x4 acc[2][2];
#pragma unroll
  for (int i = 0; i < 2; ++i)
#pragma unroll
    for (int j = 0; j < 2; ++j) acc[i][j] = (f32x4){0.f, 0.f, 0.f, 0.f};

  gemm_pipe(As, Bs, ag, bg, DIM >> 5, tid, wm, wn, mr, quad, acc);

  const int r0 = quad * 4;
#pragma unroll
  for (int i = 0; i < 2; ++i)
#pragma unroll
    for (int j = 0; j < 2; ++j) {
      int gn = wn * 32 + j * 16 + mr;
      float bv = bias[gn];
#pragma unroll
      for (int rr = 0; rr < 4; ++rr)
        ls[wm * 32 + i * 16 + r0 + rr][gn] = acc[i][j][rr] + bv;
    }
  __syncthreads();
#pragma unroll
  for (int rr2 = 0; rr2 < 16; ++rr2) {
    int row = wave * 16 + rr2;
    float v = ls[row][lane];
    float mx = v;
#pragma unroll
    for (int o = 32; o; o >>= 1) mx = fmaxf(mx, __shfl_xor(mx, o));
    float e = __expf(v - mx);
    float s = e;
#pragma unroll
    for (int o = 32; o; o >>= 1) s += __shfl_xor(s, o);
    out[(size_t)(rowBase + row) * NTPL + lane] = e / s;
  }
}

// ---------------- fused word attention: per-wave online softmax, no per-word syncs ----
__global__ __launch_bounds__(256) void attn_k(
    const float* __restrict__ x, const float* __restrict__ attn_w,
    const float* __restrict__ attn_b, const float* __restrict__ feats,
    float* __restrict__ words, float* __restrict__ ct) {
  const int b = blockIdx.x;
  const int tid = threadIdx.x;
  const int wave = tid >> 6, lane = tid & 63;
  const float* fb = feats + (size_t)b * SLEN * DIM;

  float4 vj[4];
#pragma unroll
  for (int j = 0; j < 4; ++j) {
    int d = 4 * lane + 256 * j;
    float4 xv = *(const float4*)(x + (size_t)b * DIM + d);
    float4 aw = *(const float4*)(attn_w + d);
    vj[j] = make_float4(xv.x * aw.x, xv.y * aw.y, xv.z * aw.z, xv.w * aw.w);
  }
  const float ab = attn_b[0];

  __shared__ float s_acc[4][DIM];
  __shared__ float s_m[4], s_l[4], s_sc[SLEN];

  float m = -1e30f, l = 0.f;
  float4 acc[4];
#pragma unroll
  for (int j = 0; j < 4; ++j) acc[j] = make_float4(0.f, 0.f, 0.f, 0.f);

  float4 f[4];
  {
    const float* fr = fb + (size_t)wave * DIM;
#pragma unroll
    for (int j = 0; j < 4; ++j) f[j] = *(const float4*)(fr + 4 * lane + 256 * j);
  }

  for (int s = wave; s < SLEN; s += 4) {
    float4 fn[4];
    if (s + 4 < SLEN) {
      const float* fr = fb + (size_t)(s + 4) * DIM;
#pragma unroll
      for (int j = 0; j < 4; ++j) fn[j] = *(const float4*)(fr + 4 * lane + 256 * j);
    }
    float p = 0.f;
#pragma unroll
    for (int j = 0; j < 4; ++j)
      p += f[j].x * vj[j].x + f[j].y * vj[j].y + f[j].z * vj[j].z + f[j].w * vj[j].w;
#pragma unroll
    for (int o = 32; o; o >>= 1) p += __shfl_xor(p, o);
    float score = p + ab;
    if (lane == 0) s_sc[s] = score;

    float mn = fmaxf(m, score);
    float scale = __expf(m - mn);
    float w = __expf(score - mn);
    l = l * scale + w;
#pragma unroll
    for (int j = 0; j < 4; ++j) {
      acc[j].x = acc[j].x * scale + w * f[j].x;
      acc[j].y = acc[j].y * scale + w * f[j].y;
      acc[j].z = acc[j].z * scale + w * f[j].z;
      acc[j].w = acc[j].w * scale + w * f[j].w;
    }
    m = mn;
    if (s + 4 < SLEN) {
#pragma unroll
      for (int j = 0; j < 4; ++j) f[j] = fn[j];
    }
  }

#pragma unroll
  for (int j = 0; j < 4; ++j)
    *(float4*)&s_acc[wave][4 * lane + 256 * j] = acc[j];
  if (lane == 0) { s_m[wave] = m; s_l[wave] = l; }
  __syncthreads();

  const float gm = fmaxf(fmaxf(s_m[0], s_m[1]), fmaxf(s_m[2], s_m[3]));
  float sc0 = __expf(s_m[0] - gm), sc1 = __expf(s_m[1] - gm);
  float sc2 = __expf(s_m[2] - gm), sc3 = __expf(s_m[3] - gm);
  const float L = s_l[0] * sc0 + s_l[1] * sc1 + s_l[2] * sc2 + s_l[3] * sc3;
  const float inv = 1.f / L;

  float4 a0 = *(const float4*)&s_acc[0][4 * tid];
  float4 a1 = *(const float4*)&s_acc[1][4 * tid];
  float4 a2 = *(const float4*)&s_acc[2][4 * tid];
  float4 a3 = *(const float4*)&s_acc[3][4 * tid];
  float4 o;
  o.x = (a0.x * sc0 + a1.x * sc1 + a2.x * sc2 + a3.x * sc3) * inv;
  o.y = (a0.y * sc0 + a1.y * sc1 + a2.y * sc2 + a3.y * sc3) * inv;
  o.z = (a0.z * sc0 + a1.z * sc1 + a2.z * sc2 + a3.z * sc3) * inv;
  o.w = (a0.w * sc0 + a1.w * sc1 + a2.w * sc2 + a3.w * sc3) * inv;
  ((float4*)(ct + (size_t)b * DIM))[tid] = o;

  if (tid < SLEN) words[(size_t)b * SLEN + tid] = __expf(s_sc[tid] - gm) * inv;
}

extern "C" void kernel_launch(void* const* d_in, const int* in_sizes, int n_in,
                              void* d_out, int out_size, void* d_ws, size_t ws_size,
                              hipStream_t stream) {
  const float* feats = (const float*)d_in[0];
  const float* tsent = (const float*)d_in[1];
  const float* tq    = (const float*)d_in[2];
  const int*   tstep = (const int*)d_in[3];
  const float* W1w = (const float*)d_in[4];
  const float* W1b = (const float*)d_in[5];
  const float* W2w = (const float*)d_in[6];
  const float* W2b = (const float*)d_in[7];
  const float* m1w = (const float*)d_in[8];
  const float* m1b = (const float*)d_in[9];
  const float* m2w = (const float*)d_in[10];
  const float* m2b = (const float*)d_in[11];
  const float* m3w = (const float*)d_in[12];
  const float* m3b = (const float*)d_in[13];
  const float* attw = (const float*)d_in[14];
  const float* attb = (const float*)d_in[15];

  char* p = (char*)d_ws;
  auto alloc = [&](size_t bytes) { char* q = p; p += (bytes + 255) & ~(size_t)255; return q; };
  int*  perm   = (int*)alloc(BATCH * 4);
  int*  bstart = (int*)alloc(17 * 4);
  bf16* tsbf = (bf16*)alloc((size_t)BATCH * DIM * 2);
  bf16* W1bf = (bf16*)alloc((size_t)TMAX * DIM * DIM * 2);
  bf16* W2bf = (bf16*)alloc((size_t)DIM * 2 * DIM * 2);
  bf16* m1bf = (bf16*)alloc((size_t)DIM * DIM * 2);
  bf16* m2bf = (bf16*)alloc((size_t)DIM * DIM * 2);
  bf16* m3bf = (bf16*)alloc((size_t)NTPL * DIM * 2);
  bf16* xcat = (bf16*)alloc((size_t)BATCH * 2 * DIM * 2);  // [x1 | tq] bf16, lda=2048
  bf16* xbf  = (bf16*)alloc((size_t)BATCH * DIM * 2);
  float* xf  = (float*)alloc((size_t)BATCH * DIM * 4);     // fp32 x for attention
  bf16* h1   = (bf16*)alloc((size_t)BATCH * DIM * 2);
  bf16* h2   = (bf16*)alloc((size_t)BATCH * DIM * 2);

  float* out_td = (float*)d_out;
  float* out_w  = out_td + (size_t)BATCH * NTPL;
  float* out_ct = out_w + (size_t)BATCH * SLEN;

  // 1 launch: all conversions + tq scatter + time-step bucketing
  prep_k<<<24641, 256, 0, stream>>>(W1w, W1bf, tsent, tsbf, W2w, W2bf,
                                    m1w, m1bf, m2w, m2bf, m3w, m3bf,
                                    tq, xcat, tstep, perm, bstart);
  // x1 (gathered, per-t) -> xcat[:, 0:DIM]
  gemm_stage1<<<dim3(DIM / 64, BATCH / 64, TMAX), 256, 0, stream>>>(
      tsbf, W1bf, W1b, perm, bstart, xcat);
  // x = xcat @ W2^T + b (K=2048), fp32 copy for attention
  gemm_bt64<<<dim3(DIM / 64, BATCH / 64), 256, 0, stream>>>(
      xcat, 2 * DIM, W2bf, 2 * DIM, W2b, xbf, DIM, xf, DIM, 2 * DIM, 0);
  // h1 = relu(x @ m1^T + b)
  gemm_bt64<<<dim3(DIM / 64, BATCH / 64), 256, 0, stream>>>(
      xbf, DIM, m1bf, DIM, m1b, h1, DIM, nullptr, DIM, DIM, 1);
  // h2 = relu(h1 @ m2^T + b)
  gemm_bt64<<<dim3(DIM / 64, BATCH / 64), 256, 0, stream>>>(
      h1, DIM, m2bf, DIM, m2b, h2, DIM, nullptr, DIM, DIM, 1);
  // template_distribution = softmax(h2 @ m3^T + b), fused
  gemm_m3sm<<<BATCH / 64, 256, 0, stream>>>(h2, m3bf, m3b, out_td);
  // word attention + c_t
  attn_k<<<BATCH, 256, 0, stream>>>(xf, attw, attb, feats, out_w, out_ct);
}